// Round 19
// baseline (307.918 us; speedup 1.0000x reference)
//
#include <hip/hip_runtime.h>

#define LBL 64
#define TT 1024
#define BB 256
#define BOS 62
#define EOS 63
#define NEGV -10000.0f

typedef float v2f __attribute__((ext_vector_type(2)));
typedef float v4f __attribute__((ext_vector_type(4)));

__device__ __forceinline__ float rl_f(float v, int l) {
    return __uint_as_float(__builtin_amdgcn_readlane(__float_as_uint(v), l));
}
__device__ __forceinline__ int acq(int* p) {
    return __hip_atomic_load(p, __ATOMIC_ACQUIRE, __HIP_MEMORY_SCOPE_WORKGROUP);
}
__device__ __forceinline__ void rel(int* p, int v) {
    __hip_atomic_store(p, v, __ATOMIC_RELEASE, __HIP_MEMORY_SCOPE_WORKGROUP);
}

// FUSED, one block per sentence, 4 waves (1/SIMD):
//   wave 0  = serial value-only forward (r16-proven) + backtrack
//   waves 1-3 = bp recompute, LDS-FREE main loop (equality-mask argmax in
//     registers) -> no contention with the producer's LDS critical path.
// Ticket (LDS acquire/release) publishes 8-step windows; consumers lag <=1.
__global__ __launch_bounds__(256, 1) void viterbi_fused(
    const float* __restrict__ X, const float* __restrict__ trans,
    float* __restrict__ out)
{
    __shared__ float msml[TT/8][LBL];                // 32 KiB boundary m rows
    __shared__ unsigned bpw[TT/4][LBL];              // 64 KiB packed bp words
    __shared__ __align__(16) float fvrow[LBL];       // producer broadcast row
    __shared__ unsigned char path_s[TT];
    __shared__ int ticket;

    const int tid  = threadIdx.x;
    const int lane = tid & 63;                  // label index n
    const int wv   = __builtin_amdgcn_readfirstlane(tid >> 6);
    const int b    = blockIdx.x;

    if (tid == 0) ticket = 0;
    __syncthreads();

    int bi = 0;                                 // wave 0 terminal tag

    if (wv == 0) {
        // ---------------- producer: value-only serial forward ----------------
        v2f tc2[32];                            // T[2i..2i+1][n] packed
#pragma unroll
        for (int i = 0; i < 32; ++i) {
            tc2[i][0] = trans[(2*i)   * LBL + lane];
            tc2[i][1] = trans[(2*i+1) * LBL + lane];
        }
        const float* Xb = X + (size_t)b * TT * LBL + lane;

        float fvv = (lane == BOS) ? 0.0f : NEGV;
        fvrow[lane] = fvv;
        v4f vq[16];
#pragma unroll
        for (int g = 0; g < 16; ++g) vq[g] = ((const v4f*)fvrow)[g];

        auto STEP = [&](float e) -> float {
            float vgs[8];
#pragma unroll
            for (int g = 0; g < 8; ++g) {
                const v4f fa = vq[2*g];
                const v4f fb = vq[2*g + 1];
                v2f s0 = __builtin_shufflevector(fa, fa, 0, 1) + tc2[4*g+0];
                v2f s1 = __builtin_shufflevector(fa, fa, 2, 3) + tc2[4*g+1];
                v2f s2 = __builtin_shufflevector(fb, fb, 0, 1) + tc2[4*g+2];
                v2f s3 = __builtin_shufflevector(fb, fb, 2, 3) + tc2[4*g+3];
                v2f w0 = __builtin_elementwise_max(s0, s1);   // v_pk_max_f32
                v2f w1 = __builtin_elementwise_max(s2, s3);
                v2f w  = __builtin_elementwise_max(w0, w1);
                vgs[g] = fmaxf(w[0], w[1]);
            }
            const float m =
                fmaxf(fmaxf(fmaxf(vgs[0], vgs[1]), fmaxf(vgs[2], vgs[3])),
                      fmaxf(fmaxf(vgs[4], vgs[5]), fmaxf(vgs[6], vgs[7])));
            fvv = m + e;                  // exact f32 add == numpy
            fvrow[lane] = fvv;
            __builtin_amdgcn_sched_barrier(0);
            const v4f* fr = (const v4f*)fvrow;   // prefetch next step (DS FIFO)
#pragma unroll
            for (int g = 0; g < 16; ++g) vq[g] = fr[g];
            __builtin_amdgcn_sched_barrier(0);
            return m;
        };

        float eC[8], eN[8];
#pragma unroll
        for (int j = 0; j < 8; ++j) eC[j] = Xb[(size_t)j * LBL];

        for (int base = 0; base < TT; base += 8) {
            if (base + 8 < TT) {                 // uniform branch
#pragma unroll
                for (int j = 0; j < 8; ++j)
                    eN[j] = Xb[(size_t)(base + 8 + j) * LBL];
            }
            float mlast = 0.0f;
#pragma unroll
            for (int j = 0; j < 8; ++j) mlast = STEP(eC[j]);
            const int g = base >> 3;
            msml[g][lane] = mlast;               // boundary m row -> LDS
            rel(&ticket, g + 1);                 // publish window g done
#pragma unroll
            for (int j = 0; j < 8; ++j) eC[j] = eN[j];
        }

        // termination + wave argmax (butterfly, lower index wins ties)
        float bv = fvv + trans[lane * LBL + EOS];
        bi = lane;
#pragma unroll
        for (int d = 1; d < 64; d <<= 1) {
            float ov = __shfl_xor(bv, d, 64);
            int   oi = __shfl_xor(bi, d, 64);
            if (ov > bv || (ov == bv && oi < bi)) { bv = ov; bi = oi; }
        }
        if (lane == 0) out[b] = bv;
    } else {
        // -------- consumers: bp recompute, LDS-FREE main loop --------
        float tc[LBL];
#pragma unroll
        for (int p = 0; p < LBL; ++p) tc[p] = trans[p * LBL + lane];

        const int cw = wv - 1;
        for (int c = cw; c < TT/8; c += 3) {
            if (c > 0) while (acq(&ticket) < c) __builtin_amdgcn_s_sleep(2);

            float fvp;                           // fv_{8c-1}[lane]
            if (c == 0) fvp = (lane == BOS) ? 0.0f : NEGV;
            else fvp = msml[c-1][lane]
                     + X[((size_t)b * TT + (8*c - 1)) * LBL + lane];

            const float* Xb = X + ((size_t)b * TT + 8*c) * LBL + lane;

            unsigned pk0 = 0, pk1 = 0;
#pragma unroll
            for (int j = 0; j < 8; ++j) {
                float e = Xb[(size_t)j * LBL];
                float vg[8]; unsigned km[8];
#pragma unroll
                for (int g = 0; g < 8; ++g) {
                    float s0 = rl_f(fvp, 8*g+0) + tc[8*g+0];
                    float s1 = rl_f(fvp, 8*g+1) + tc[8*g+1];
                    float s2 = rl_f(fvp, 8*g+2) + tc[8*g+2];
                    float s3 = rl_f(fvp, 8*g+3) + tc[8*g+3];
                    float s4 = rl_f(fvp, 8*g+4) + tc[8*g+4];
                    float s5 = rl_f(fvp, 8*g+5) + tc[8*g+5];
                    float s6 = rl_f(fvp, 8*g+6) + tc[8*g+6];
                    float s7 = rl_f(fvp, 8*g+7) + tc[8*g+7];
                    // same fmax ops as producer's pk_max -> bitwise equal
                    float v = fmaxf(fmaxf(fmaxf(s0, s1), fmaxf(s2, s3)),
                                    fmaxf(fmaxf(s4, s5), fmaxf(s6, s7)));
                    vg[g] = v;
                    // registers-only equality mask of within-group hits
                    km[g] = (s0 == v ? 1u   : 0u) | (s1 == v ? 2u   : 0u)
                          | (s2 == v ? 4u   : 0u) | (s3 == v ? 8u   : 0u)
                          | (s4 == v ? 16u  : 0u) | (s5 == v ? 32u  : 0u)
                          | (s6 == v ? 64u  : 0u) | (s7 == v ? 128u : 0u);
                }
                const float m = fmaxf(
                    fmaxf(fmaxf(vg[0], vg[1]), fmaxf(vg[2], vg[3])),
                    fmaxf(fmaxf(vg[4], vg[5]), fmaxf(vg[6], vg[7])));

                // first group containing m + its hit mask (static chains)
                int gs = 7; unsigned kmm = km[7];
#pragma unroll
                for (int g = 6; g >= 0; --g) {
                    bool eq = (vg[g] == m);
                    gs  = eq ? g     : gs;
                    kmm = eq ? km[g] : kmm;
                }
                const int k = __builtin_ctz(kmm);    // first k with s==m
                const unsigned kk = (unsigned)((gs << 3) | k);

                if (j < 4) pk0 |= kk << (8*j);
                else       pk1 |= kk << (8*(j-4));
                fvp = m + e;                         // exact chain within chunk
            }
            bpw[2*c][lane]     = pk0;                // steps 8c..8c+3
            bpw[2*c + 1][lane] = pk1;                // steps 8c+4..8c+7
        }
    }

    __syncthreads();   // all bp words visible; producer done

    if (wv == 0) {
        // ---------------- backtrack from LDS (readlane chase) ----------------
        int stag = bi;                           // uniform (butterfly converged)
        unsigned w[8];
#pragma unroll
        for (int i = 0; i < 8; ++i) w[i] = bpw[255 - i][lane];

        for (int t4 = 255; t4 >= 0; t4 -= 8) {
            unsigned nw[8];
            const int nbase = t4 - 8;
#pragma unroll
            for (int i = 0; i < 8; ++i) {
                int idx = nbase - i; if (idx < 0) idx = 0;
                nw[i] = bpw[idx][lane];
            }
#pragma unroll
            for (int i = 0; i < 8; ++i) {
                const int tt4 = t4 - i;
                const unsigned ww = w[i];
#pragma unroll
                for (int sub = 3; sub >= 0; --sub) {
                    const int t = 4 * tt4 + sub;
                    if (lane == (t & 63)) path_s[t] = (unsigned char)stag;
                    unsigned wr = (unsigned)__builtin_amdgcn_readlane((int)ww, stag);
                    stag = (int)((wr >> (8 * sub)) & 0xFFu);
                }
            }
#pragma unroll
            for (int i = 0; i < 8; ++i) w[i] = nw[i];
        }
    }
    __syncthreads();

    // cooperative float path write (all 256 threads)
    float* po = out + BB + (size_t)b * TT;
#pragma unroll
    for (int i = 0; i < TT / 256; ++i)
        po[i * 256 + tid] = (float)path_s[i * 256 + tid];
}

extern "C" void kernel_launch(void* const* d_in, const int* in_sizes, int n_in,
                              void* d_out, int out_size, void* d_ws, size_t ws_size,
                              hipStream_t stream)
{
    const float* X     = (const float*)d_in[0];   // [256, 1024, 64]
    const float* trans = (const float*)d_in[1];   // [64, 64]
    float* out = (float*)d_out;                   // [256] scores ++ [256*1024] path

    viterbi_fused<<<dim3(BB), dim3(256), 0, stream>>>(X, trans, out);
}

// Round 20
// 263.321 us; speedup vs baseline: 1.1694x; 1.1694x over previous
//
#include <hip/hip_runtime.h>

#define LBL 64
#define TT 1024
#define BB 256
#define BOS 62
#define EOS 63
#define NEGV -10000.0f

typedef float v2f __attribute__((ext_vector_type(2)));
typedef float v4f __attribute__((ext_vector_type(4)));

__device__ __forceinline__ float rl_f(float v, int l) {
    return __uint_as_float(__builtin_amdgcn_readlane(__float_as_uint(v), l));
}
__device__ __forceinline__ int acq(int* p) {
    return __hip_atomic_load(p, __ATOMIC_ACQUIRE, __HIP_MEMORY_SCOPE_WORKGROUP);
}
__device__ __forceinline__ void rel(int* p, int v) {
    __hip_atomic_store(p, v, __ATOMIC_RELEASE, __HIP_MEMORY_SCOPE_WORKGROUP);
}

// FUSED, one block per sentence, 4 waves (1/SIMD):
//   wave 0  = serial value-only forward (r16-proven) + backtrack, setprio(1)
//   waves 1-3 = bp recompute (r18 shfl+tlds form), 8-step RUNTIME inner loop
//     -> consumer code ~1.9KB (was ~15KB unrolled): no I-cache thrash of the
//        producer's hot loop. X load issues at body top, consumed at bottom.
// Ticket (LDS acquire/release) publishes 8-step windows; consumers lag <=1.
__global__ __launch_bounds__(256, 1) void viterbi_fused(
    const float* __restrict__ X, const float* __restrict__ trans,
    float* __restrict__ out)
{
    __shared__ float msml[TT/8][LBL];                // 32 KiB boundary m rows
    __shared__ unsigned bpw[TT/4][LBL];              // 64 KiB packed bp words
    __shared__ __align__(16) float tlds[LBL * LBL];  // 16 KiB [p][n]
    __shared__ __align__(16) float fvrow[LBL];       // producer broadcast row
    __shared__ unsigned char path_s[TT];
    __shared__ int ticket;

    const int tid  = threadIdx.x;
    const int lane = tid & 63;                  // label index n
    const int wv   = __builtin_amdgcn_readfirstlane(tid >> 6);
    const int b    = blockIdx.x;

    // cooperative tlds init (wave wv writes rows [16wv,16wv+16))
#pragma unroll
    for (int i = 0; i < 16; ++i)
        tlds[(wv * 16 + i) * LBL + lane] = trans[(wv * 16 + i) * LBL + lane];
    if (tid == 0) ticket = 0;
    __syncthreads();

    int bi = 0;                                 // wave 0 terminal tag

    if (wv == 0) {
        __builtin_amdgcn_s_setprio(1);          // serial chain wins arbitration
        // ---------------- producer: value-only serial forward ----------------
        v2f tc2[32];                            // T[2i..2i+1][n] packed
#pragma unroll
        for (int i = 0; i < 32; ++i) {
            tc2[i][0] = trans[(2*i)   * LBL + lane];
            tc2[i][1] = trans[(2*i+1) * LBL + lane];
        }
        const float* Xb = X + (size_t)b * TT * LBL + lane;

        float fvv = (lane == BOS) ? 0.0f : NEGV;
        fvrow[lane] = fvv;
        v4f vq[16];
#pragma unroll
        for (int g = 0; g < 16; ++g) vq[g] = ((const v4f*)fvrow)[g];

        auto STEP = [&](float e) -> float {
            float vgs[8];
#pragma unroll
            for (int g = 0; g < 8; ++g) {
                const v4f fa = vq[2*g];
                const v4f fb = vq[2*g + 1];
                v2f s0 = __builtin_shufflevector(fa, fa, 0, 1) + tc2[4*g+0];
                v2f s1 = __builtin_shufflevector(fa, fa, 2, 3) + tc2[4*g+1];
                v2f s2 = __builtin_shufflevector(fb, fb, 0, 1) + tc2[4*g+2];
                v2f s3 = __builtin_shufflevector(fb, fb, 2, 3) + tc2[4*g+3];
                v2f w0 = __builtin_elementwise_max(s0, s1);   // v_pk_max_f32
                v2f w1 = __builtin_elementwise_max(s2, s3);
                v2f w  = __builtin_elementwise_max(w0, w1);
                vgs[g] = fmaxf(w[0], w[1]);
            }
            const float m =
                fmaxf(fmaxf(fmaxf(vgs[0], vgs[1]), fmaxf(vgs[2], vgs[3])),
                      fmaxf(fmaxf(vgs[4], vgs[5]), fmaxf(vgs[6], vgs[7])));
            fvv = m + e;                  // exact f32 add == numpy
            fvrow[lane] = fvv;
            __builtin_amdgcn_sched_barrier(0);
            const v4f* fr = (const v4f*)fvrow;   // prefetch next step (DS FIFO)
#pragma unroll
            for (int g = 0; g < 16; ++g) vq[g] = fr[g];
            __builtin_amdgcn_sched_barrier(0);
            return m;
        };

        float eC[8], eN[8];
#pragma unroll
        for (int j = 0; j < 8; ++j) eC[j] = Xb[(size_t)j * LBL];

        for (int base = 0; base < TT; base += 8) {
            if (base + 8 < TT) {                 // uniform branch
#pragma unroll
                for (int j = 0; j < 8; ++j)
                    eN[j] = Xb[(size_t)(base + 8 + j) * LBL];
            }
            float mlast = 0.0f;
#pragma unroll
            for (int j = 0; j < 8; ++j) mlast = STEP(eC[j]);
            const int g = base >> 3;
            msml[g][lane] = mlast;               // boundary m row -> LDS
            rel(&ticket, g + 1);                 // publish window g done
#pragma unroll
            for (int j = 0; j < 8; ++j) eC[j] = eN[j];
        }

        // termination + wave argmax (butterfly, lower index wins ties)
        float bv = fvv + trans[lane * LBL + EOS];
        bi = lane;
#pragma unroll
        for (int d = 1; d < 64; d <<= 1) {
            float ov = __shfl_xor(bv, d, 64);
            int   oi = __shfl_xor(bi, d, 64);
            if (ov > bv || (ov == bv && oi < bi)) { bv = ov; bi = oi; }
        }
        if (lane == 0) out[b] = bv;
    } else {
        // -------- consumers: bp recompute (r18 form), runtime inner loop --------
        float tc[LBL];
#pragma unroll
        for (int p = 0; p < LBL; ++p) tc[p] = trans[p * LBL + lane];

        const float* XbS = X + (size_t)b * TT * LBL + lane;
        const int cw = wv - 1;
        for (int c = cw; c < TT/8; c += 3) {
            if (c > 0) while (acq(&ticket) < c) __builtin_amdgcn_s_sleep(2);

            float fvp;                           // fv_{8c-1}[lane]
            if (c == 0) fvp = (lane == BOS) ? 0.0f : NEGV;
            else fvp = msml[c-1][lane] + XbS[(size_t)(8*c - 1) * LBL];

            unsigned pk0 = 0, pk1 = 0;
            for (int j = 0; j < 8; ++j) {        // RUNTIME loop: ~1.9KB body
                float e = XbS[(size_t)(8*c + j) * LBL];   // used at body end

                float vg[8];
#pragma unroll
                for (int g = 0; g < 8; ++g) {
                    float s0 = rl_f(fvp, 8*g+0) + tc[8*g+0];
                    float s1 = rl_f(fvp, 8*g+1) + tc[8*g+1];
                    float s2 = rl_f(fvp, 8*g+2) + tc[8*g+2];
                    float s3 = rl_f(fvp, 8*g+3) + tc[8*g+3];
                    float s4 = rl_f(fvp, 8*g+4) + tc[8*g+4];
                    float s5 = rl_f(fvp, 8*g+5) + tc[8*g+5];
                    float s6 = rl_f(fvp, 8*g+6) + tc[8*g+6];
                    float s7 = rl_f(fvp, 8*g+7) + tc[8*g+7];
                    vg[g] = fmaxf(fmaxf(fmaxf(s0, s1), fmaxf(s2, s3)),
                                  fmaxf(fmaxf(s4, s5), fmaxf(s6, s7)));
                }
                const float m = fmaxf(
                    fmaxf(fmaxf(vg[0], vg[1]), fmaxf(vg[2], vg[3])),
                    fmaxf(fmaxf(vg[4], vg[5]), fmaxf(vg[6], vg[7])));

                int gs = 7;                      // first group containing m
#pragma unroll
                for (int g = 6; g >= 0; --g) gs = (vg[g] == m) ? g : gs;
                const int pbase = gs << 3;

                // recompute group gs's 8 sums (same IEEE adds -> bitwise ==)
                const float* tg = &tlds[pbase * LBL + lane];
                float q0 = __shfl(fvp, pbase + 0, 64) + tg[0 * LBL];
                float q1 = __shfl(fvp, pbase + 1, 64) + tg[1 * LBL];
                float q2 = __shfl(fvp, pbase + 2, 64) + tg[2 * LBL];
                float q3 = __shfl(fvp, pbase + 3, 64) + tg[3 * LBL];
                float q4 = __shfl(fvp, pbase + 4, 64) + tg[4 * LBL];
                float q5 = __shfl(fvp, pbase + 5, 64) + tg[5 * LBL];
                float q6 = __shfl(fvp, pbase + 6, 64) + tg[6 * LBL];
                float q7 = __shfl(fvp, pbase + 7, 64) + tg[7 * LBL];
                int k = 7;
                k = (q6 == m) ? 6 : k;
                k = (q5 == m) ? 5 : k;
                k = (q4 == m) ? 4 : k;
                k = (q3 == m) ? 3 : k;
                k = (q2 == m) ? 2 : k;
                k = (q1 == m) ? 1 : k;
                k = (q0 == m) ? 0 : k;           // lowest k = first occurrence
                const unsigned kk = (unsigned)(pbase | k);

                const unsigned sh = 8u * (unsigned)(j & 3);
                if (j < 4) pk0 |= kk << sh;
                else       pk1 |= kk << sh;
                fvp = m + e;                     // exact chain within chunk
            }
            bpw[2*c][lane]     = pk0;            // steps 8c..8c+3
            bpw[2*c + 1][lane] = pk1;            // steps 8c+4..8c+7
        }
    }

    __syncthreads();   // all bp words visible; producer done

    if (wv == 0) {
        // ---------------- backtrack from LDS (readlane chase) ----------------
        int stag = bi;                           // uniform (butterfly converged)
        unsigned w[8];
#pragma unroll
        for (int i = 0; i < 8; ++i) w[i] = bpw[255 - i][lane];

        for (int t4 = 255; t4 >= 0; t4 -= 8) {
            unsigned nw[8];
            const int nbase = t4 - 8;
#pragma unroll
            for (int i = 0; i < 8; ++i) {
                int idx = nbase - i; if (idx < 0) idx = 0;
                nw[i] = bpw[idx][lane];
            }
#pragma unroll
            for (int i = 0; i < 8; ++i) {
                const int tt4 = t4 - i;
                const unsigned ww = w[i];
#pragma unroll
                for (int sub = 3; sub >= 0; --sub) {
                    const int t = 4 * tt4 + sub;
                    if (lane == (t & 63)) path_s[t] = (unsigned char)stag;
                    unsigned wr = (unsigned)__builtin_amdgcn_readlane((int)ww, stag);
                    stag = (int)((wr >> (8 * sub)) & 0xFFu);
                }
            }
#pragma unroll
            for (int i = 0; i < 8; ++i) w[i] = nw[i];
        }
    }
    __syncthreads();

    // cooperative float path write (all 256 threads)
    float* po = out + BB + (size_t)b * TT;
#pragma unroll
    for (int i = 0; i < TT / 256; ++i)
        po[i * 256 + tid] = (float)path_s[i * 256 + tid];
}

extern "C" void kernel_launch(void* const* d_in, const int* in_sizes, int n_in,
                              void* d_out, int out_size, void* d_ws, size_t ws_size,
                              hipStream_t stream)
{
    const float* X     = (const float*)d_in[0];   // [256, 1024, 64]
    const float* trans = (const float*)d_in[1];   // [64, 64]
    float* out = (float*)d_out;                   // [256] scores ++ [256*1024] path

    viterbi_fused<<<dim3(BB), dim3(256), 0, stream>>>(X, trans, out);
}